// Round 1
// baseline (36255.573 us; speedup 1.0000x reference)
//
#include <hip/hip_runtime.h>
#include <hip/hip_cooperative_groups.h>
#include <math.h>

namespace cg = cooperative_groups;

namespace {
constexpr int BATCH = 128;
constexpr int SEQ   = 512;
constexpr int EMBD  = 512;
constexpr int NL    = 32;
constexpr int BOSTAG = 1;
constexpr int EOSTAG = 2;
}

// hbuf layout: [2 parity][2 dir][512 u][128 b]
__device__ __forceinline__ size_t hoff(int par, int dir, int u, int b) {
  return (((size_t)(par * 2 + dir) * 512 + u) * BATCH + b);
}

__global__ __launch_bounds__(256, 1)
void bilstm_coop(const int* __restrict__ x,
                 const float* __restrict__ emb,
                 const float* __restrict__ Wih_f, const float* __restrict__ Whh_f, const float* __restrict__ bf,
                 const float* __restrict__ Wih_b, const float* __restrict__ Whh_b, const float* __restrict__ bbias,
                 const float* __restrict__ Wout, const float* __restrict__ bout,
                 float* __restrict__ hbuf, float* __restrict__ em)
{
  cg::grid_group grid = cg::this_grid();
  __shared__ float in_t[64][128];   // [k][b] transposed input tile
  __shared__ float Wt[16][64];      // 16 gate-rows x 64 k
  __shared__ float g_lds[16][128];  // gate outputs [row][b]
  __shared__ float hcol[512];       // one h column for emission phase

  const int tid = threadIdx.x;
  const int bi  = blockIdx.x;
  const int dir = bi >> 7;             // 0 = fwd, 1 = bwd
  const int u0  = (bi & 127) * 4;      // 4 hidden units per block

  const float* Wih = dir ? Wih_b : Wih_f;
  const float* Whh = dir ? Whh_b : Whh_f;
  const float* bv  = dir ? bbias : bf;

  // zero parity-1 h buffer (initial h state)
  {
    size_t g0 = ((size_t)bi * 256 + tid) * 2;
    hbuf[2ull * 512 * BATCH + g0]     = 0.f;
    hbuf[2ull * 512 * BATCH + g0 + 1] = 0.f;
  }

  // GEMM micro-tile mapping: 4 batches x 2 rows per thread
  const int bq = tid & 31;             // batch quad: b = bq*4 + 0..3
  const int rp = tid >> 5;             // row pair: rows 2rp, 2rp+1
  const int r0 = rp * 2, r1 = rp * 2 + 1;
  // local row j -> global W row: gate = j&3, uu = j>>2
  const int grow0 = (r0 & 3) * 512 + u0 + (r0 >> 2);
  const int grow1 = (r1 & 3) * 512 + u0 + (r1 >> 2);
  const float bias0 = bv[grow0];
  const float bias1 = bv[grow1];

  // staging mappings
  const int emb_b    = tid >> 1;       // batch row for emb chunks
  const int emb_half = tid & 1;        // which 32-col half
  const int h_k      = tid >> 2;       // k row for h chunks
  const int h_q      = tid & 3;        // 32-col quarter
  const int w_r      = tid >> 4;       // Wt row
  const int w_c4     = (tid & 15) * 4; // Wt col (float4)
  const int w_grow   = (w_r & 3) * 512 + u0 + (w_r >> 2);

  // state-update mapping: thread owns states (u0+uloc, sb0) and (u0+uloc, sb0+1)
  const int uloc = tid >> 6;           // 0..3
  const int sb0  = (tid & 63) * 2;     // 0..126
  float cst0 = 0.f, cst1 = 0.f;

  grid.sync();

  for (int s = 0; s <= SEQ; ++s) {
    // ---- emission phase for h produced at step s-1 ----
    if (s >= 1) {
      const int tprev = dir ? (SEQ - s) : (s - 1);
      const int bb_ = bi & 127;
      const float* hsrc = hbuf + hoff((s - 1) & 1, dir, 0, 0);
      hcol[tid]       = hsrc[(size_t)tid * BATCH + bb_];
      hcol[tid + 256] = hsrc[(size_t)(tid + 256) * BATCH + bb_];
      __syncthreads();
      const int wv = tid >> 6, ln = tid & 63;
      const bool first = dir ? (tprev >= 256) : (tprev < 256);
      #pragma unroll
      for (int li = 0; li < 8; ++li) {
        const int l = wv * 8 + li;
        const float* wrow = Wout + (size_t)l * 1024 + dir * 512 + ln * 8;
        const float* hc = &hcol[ln * 8];
        float p = hc[0]*wrow[0] + hc[1]*wrow[1] + hc[2]*wrow[2] + hc[3]*wrow[3]
                + hc[4]*wrow[4] + hc[5]*wrow[5] + hc[6]*wrow[6] + hc[7]*wrow[7];
        #pragma unroll
        for (int off = 32; off >= 1; off >>= 1) p += __shfl_down(p, off);
        if (ln == 0) {
          float* dst = em + ((size_t)bb_ * SEQ + tprev) * NL + l;
          *dst = first ? (p + bout[l]) : (*dst + p);
        }
      }
      // hcol is only rewritten after the next grid.sync
    }

    // ---- LSTM step ----
    if (s < SEQ) {
      const int t = dir ? (SEQ - 1 - s) : s;
      const float* hprev = hbuf + hoff((s + 1) & 1, dir, 0, 0);
      float* hout        = hbuf + hoff(s & 1, dir, 0, 0);
      const int xid = x[emb_b * SEQ + t];
      const float* embrow = emb + (size_t)xid * EMBD + emb_half * 32;

      float acc00=0,acc01=0,acc02=0,acc03=0,acc10=0,acc11=0,acc12=0,acc13=0;
      float4 pre[8];
      // prefetch chunk 0 (emb cols 0..63)
      #pragma unroll
      for (int j = 0; j < 8; ++j) pre[j] = *(const float4*)&embrow[j * 4];

      for (int c = 0; c < 16; ++c) {
        __syncthreads();               // in_t free (previous compute done)
        if (c < 8) {
          // emb chunk: transpose-scatter into in_t[k][b]
          #pragma unroll
          for (int j = 0; j < 8; ++j) {
            const int k = emb_half * 32 + j * 4;
            in_t[k + 0][emb_b] = pre[j].x;
            in_t[k + 1][emb_b] = pre[j].y;
            in_t[k + 2][emb_b] = pre[j].z;
            in_t[k + 3][emb_b] = pre[j].w;
          }
        } else {
          // h chunk: straight copy (h is stored [u][b])
          #pragma unroll
          for (int j = 0; j < 8; ++j)
            *(float4*)&in_t[h_k][h_q * 32 + j * 4] = pre[j];
        }
        // stage W tile for this chunk
        {
          const int col = c * 64 + w_c4;
          float4 wv4 = (col < 512)
              ? *(const float4*)&Wih[(size_t)w_grow * 512 + col]
              : *(const float4*)&Whh[(size_t)w_grow * 512 + col - 512];
          *(float4*)&Wt[w_r][w_c4] = wv4;
        }
        // prefetch next chunk into registers (overlaps with compute below)
        if (c + 1 < 16) {
          if (c + 1 < 8) {
            const float* src = embrow + (c + 1) * 64;
            #pragma unroll
            for (int j = 0; j < 8; ++j) pre[j] = *(const float4*)&src[j * 4];
          } else {
            const float* src = hprev + ((size_t)(c + 1 - 8) * 64 + h_k) * BATCH + h_q * 32;
            #pragma unroll
            for (int j = 0; j < 8; ++j) pre[j] = *(const float4*)&src[j * 4];
          }
        }
        __syncthreads();               // staging visible
        // compute: 64 k values
        #pragma unroll
        for (int k4 = 0; k4 < 16; ++k4) {
          const float4 w0 = *(const float4*)&Wt[r0][k4 * 4];
          const float4 w1 = *(const float4*)&Wt[r1][k4 * 4];
          float4 a;
          a = *(const float4*)&in_t[k4 * 4 + 0][bq * 4];
          acc00 += a.x*w0.x; acc01 += a.y*w0.x; acc02 += a.z*w0.x; acc03 += a.w*w0.x;
          acc10 += a.x*w1.x; acc11 += a.y*w1.x; acc12 += a.z*w1.x; acc13 += a.w*w1.x;
          a = *(const float4*)&in_t[k4 * 4 + 1][bq * 4];
          acc00 += a.x*w0.y; acc01 += a.y*w0.y; acc02 += a.z*w0.y; acc03 += a.w*w0.y;
          acc10 += a.x*w1.y; acc11 += a.y*w1.y; acc12 += a.z*w1.y; acc13 += a.w*w1.y;
          a = *(const float4*)&in_t[k4 * 4 + 2][bq * 4];
          acc00 += a.x*w0.z; acc01 += a.y*w0.z; acc02 += a.z*w0.z; acc03 += a.w*w0.z;
          acc10 += a.x*w1.z; acc11 += a.y*w1.z; acc12 += a.z*w1.z; acc13 += a.w*w1.z;
          a = *(const float4*)&in_t[k4 * 4 + 3][bq * 4];
          acc00 += a.x*w0.w; acc01 += a.y*w0.w; acc02 += a.z*w0.w; acc03 += a.w*w0.w;
          acc10 += a.x*w1.w; acc11 += a.y*w1.w; acc12 += a.z*w1.w; acc13 += a.w*w1.w;
        }
      }
      // bias + regroup gates via LDS
      *(float4*)&g_lds[r0][bq * 4] = make_float4(acc00 + bias0, acc01 + bias0, acc02 + bias0, acc03 + bias0);
      *(float4*)&g_lds[r1][bq * 4] = make_float4(acc10 + bias1, acc11 + bias1, acc12 + bias1, acc13 + bias1);
      __syncthreads();
      // gate nonlinearity + cell/h update (c persists in registers)
      #pragma unroll
      for (int e2 = 0; e2 < 2; ++e2) {
        const int b2 = sb0 + e2;
        const float gi = g_lds[uloc * 4 + 0][b2];
        const float gf = g_lds[uloc * 4 + 1][b2];
        const float gg = g_lds[uloc * 4 + 2][b2];
        const float go = g_lds[uloc * 4 + 3][b2];
        const float si = 1.f / (1.f + expf(-gi));
        const float sf = 1.f / (1.f + expf(-gf));
        const float so = 1.f / (1.f + expf(-go));
        float& cs = e2 ? cst1 : cst0;
        const float cn = sf * cs + si * tanhf(gg);
        cs = cn;
        hout[(size_t)(u0 + uloc) * BATCH + b2] = so * tanhf(cn);
      }
    }
    grid.sync();
  }
}

__global__ __launch_bounds__(64)
void viterbi_kernel(const float* __restrict__ em, const int* __restrict__ mask,
                    const float* __restrict__ trans, float* __restrict__ out)
{
  __shared__ float tr[32][33];
  __shared__ float alpha[32];
  __shared__ float fin[32];
  __shared__ unsigned char bp[SEQ][32];
  __shared__ float path[SEQ];

  const int b = blockIdx.x, tid = threadIdx.x;
  for (int i = tid; i < 1024; i += 64) tr[i >> 5][i & 31] = trans[i];
  __syncthreads();

  const float* emB = em + (size_t)b * SEQ * NL;
  if (tid < 32) alpha[tid] = tr[BOSTAG][tid] + emB[tid];
  __syncthreads();

  for (int t = 1; t < SEQ; ++t) {
    float best = -INFINITY, e = 0.f;
    int arg = 0;
    if (tid < 32) {
      e = emB[t * NL + tid];
      #pragma unroll 4
      for (int p = 0; p < 32; ++p) {
        const float sc = (alpha[p] + tr[p][tid]) + e;  // np broadcast order
        if (sc > best) { best = sc; arg = p; }          // first-occurrence argmax
      }
    }
    __syncthreads();
    if (tid < 32) {
      const float m = (float)mask[b * SEQ + t];
      alpha[tid] = m * best + (1.f - m) * alpha[tid];
      bp[t][tid] = (unsigned char)arg;
    }
    __syncthreads();
  }

  if (tid < 32) fin[tid] = alpha[tid] + tr[tid][EOSTAG];
  __syncthreads();

  if (tid == 0) {
    float best = fin[0]; int tag = 0;
    for (int n = 1; n < 32; ++n) if (fin[n] > best) { best = fin[n]; tag = n; }
    out[b] = best;
    path[SEQ - 1] = (float)tag;
    for (int k = SEQ - 2; k >= 0; --k) {
      const int prev = bp[k + 1][tag];
      if (mask[b * SEQ + k + 1] > 0) tag = prev;
      path[k] = (float)tag;
    }
  }
  __syncthreads();
  for (int idx = tid; idx < SEQ; idx += 64)
    out[BATCH + (size_t)b * SEQ + idx] = path[idx];
}

extern "C" void kernel_launch(void* const* d_in, const int* in_sizes, int n_in,
                              void* d_out, int out_size, void* d_ws, size_t ws_size,
                              hipStream_t stream) {
  (void)in_sizes; (void)n_in; (void)out_size; (void)ws_size;
  const int*   x     = (const int*)d_in[0];
  const int*   mask  = (const int*)d_in[1];
  const float* emb   = (const float*)d_in[2];
  const float* Wih_f = (const float*)d_in[3];
  const float* Whh_f = (const float*)d_in[4];
  const float* bf    = (const float*)d_in[5];
  const float* Wih_b = (const float*)d_in[6];
  const float* Whh_b = (const float*)d_in[7];
  const float* bb    = (const float*)d_in[8];
  const float* Wout  = (const float*)d_in[9];
  const float* bout  = (const float*)d_in[10];
  const float* trans = (const float*)d_in[11];
  float* out  = (float*)d_out;
  float* hbuf = (float*)d_ws;                   // 262144 floats (1 MB)
  float* em   = hbuf + 2ull * 2 * 512 * BATCH;  // 2097152 floats (8 MB)

  void* args[] = { (void*)&x, (void*)&emb,
                   (void*)&Wih_f, (void*)&Whh_f, (void*)&bf,
                   (void*)&Wih_b, (void*)&Whh_b, (void*)&bb,
                   (void*)&Wout, (void*)&bout,
                   (void*)&hbuf, (void*)&em };
  hipLaunchCooperativeKernel((void*)bilstm_coop, dim3(256), dim3(256), args, 0, stream);
  viterbi_kernel<<<dim3(128), dim3(64), 0, stream>>>(em, mask, trans, out);
}